// Round 12
// baseline (114.524 us; speedup 1.0000x reference)
//
#include <hip/hip_runtime.h>

#define IMG    512
#define TW     32
#define TH     32
#define R      5
#define KW     11
#define HB_H   (TH + 2*R)            // 42
#define W4     33                    // hb4 padded row stride (float4 cells)
#define GX     (IMG / TW)            // 16
#define GY     (IMG / TH)            // 16
#define NBATCH 32
#define NBLOCKS (GX * GY * NBATCH)   // 8192
#define NSLOTS  64
#define PERSLOT (NBLOCKS / NSLOTS)   // 128
#define C1f 0.0001f
#define C2f 0.0009f

#define SCALEF    16777216.0f        // 2^24 ; |v| <= 1024*2^24 = 2^34
#define SSHIFT    45
#define BIAS1     (1ll << 36)
#define GSHIFT    50
#define BIAS2     (1ll << 43)

#define RT_HALF   0.70710678118654752f   // sqrt(0.5): mu-channel vertical scale

typedef float v2f __attribute__((ext_vector_type(2)));

// u=x+y, v=x-y basis: 4 conv channels = 2 pk accumulators per tap.
// Vertical weights pre-scaled (mu x sqrt(0.5), S x 0.5) so the epilogue is
// pure adds/muls + v_rcp_f32 (no divide chain, no 0.5 scalings).
// LDS: 42*33*16 + 16 = 22,192 B -> 7 blocks/CU. Permutation
// pos(c) = (c>>3) + ((c&7)<<2) shared by writer/reader: conflict-light.
__global__ __launch_bounds__(256, 4) void ssim_fused_kernel(
    const float* __restrict__ x, const float* __restrict__ y,
    float* __restrict__ out, unsigned long long* __restrict__ ws)
{
    __shared__ float4 hb4[HB_H][W4];  // (mu_u, mu_v, Su, Sv) horiz-filtered
    __shared__ float  red[4];

    // normalized 1D Gaussian, sigma=1.5, k=11
    const float W[KW] = {
        0.00102838f, 0.00759874f, 0.03600077f, 0.10936075f, 0.21300553f,
        0.26601172f,
        0.21300553f, 0.10936075f, 0.03600077f, 0.00759874f, 0.00102838f};

    const int tc = blockIdx.x, tr = blockIdx.y, b = blockIdx.z;
    const int tid = threadIdx.x;
    const size_t imgBase = (size_t)b * (IMG * IMG);
    const int gr0 = tr * TH - R;
    const bool colEdge = (tc == 0) || (tc == GX - 1);

    // ========== horizontal pass: 8-px items, single trip (168 <= 256) ======
    if (tid < HB_H * 4) {
        const int rr = tid >> 2;         // staged row 0..41
        const int g  = tid & 3;          // 8-px group in row
        const int gr = gr0 + rr;
        if ((unsigned)gr < (unsigned)IMG) {
            const float4* rx = (const float4*)(x + imgBase + (size_t)gr * IMG);
            const float4* ry = (const float4*)(y + imgBase + (size_t)gr * IMG);
            const int q0 = tc * 8 + 2 * g - 2;  // 6 float4 = f[0..23]; taps f[3..20]
            float fx[24], fy[24];
            if (colEdge) {
#pragma unroll
                for (int i4 = 0; i4 < 6; ++i4) {
                    int q = q0 + i4;
                    int qc = min(max(q, 0), IMG / 4 - 1);
                    float4 vx = rx[qc], vy = ry[qc];
                    float m = (q == qc) ? 1.f : 0.f;
                    fx[4*i4+0]=vx.x*m; fx[4*i4+1]=vx.y*m; fx[4*i4+2]=vx.z*m; fx[4*i4+3]=vx.w*m;
                    fy[4*i4+0]=vy.x*m; fy[4*i4+1]=vy.y*m; fy[4*i4+2]=vy.z*m; fy[4*i4+3]=vy.w*m;
                }
            } else {
#pragma unroll
                for (int i4 = 0; i4 < 6; ++i4) {
                    float4 vx = rx[q0 + i4], vy = ry[q0 + i4];
                    fx[4*i4+0]=vx.x; fx[4*i4+1]=vx.y; fx[4*i4+2]=vx.z; fx[4*i4+3]=vx.w;
                    fy[4*i4+0]=vy.x; fy[4*i4+1]=vy.y; fy[4*i4+2]=vy.z; fy[4*i4+3]=vy.w;
                }
            }
            // j-outer / k-inner, u/v basis, all-pk accumulation
            v2f m[8], s[8];
#pragma unroll
            for (int k = 0; k < 8; ++k) { m[k] = (v2f)(0.f); s[k] = (v2f)(0.f); }
#pragma unroll
            for (int j = 0; j < 18; ++j) {        // input f[3+j]
                const float a = fx[3 + j], c = fy[3 + j];
                const v2f p  = { a + c, a - c };  // (u, v)
                const v2f pp = p * p;             // (u2, v2) pk_mul
#pragma unroll
                for (int k = 0; k < 8; ++k) {
                    const int t = j - k;
                    if (t >= 0 && t < KW) {       // constant-folds
                        const float wt = W[t];
                        m[k] += wt * p;           // pk_fma
                        s[k] += wt * pp;          // pk_fma
                    }
                }
            }
#pragma unroll
            for (int k = 0; k < 8; ++k) {
                const int pos = g + 4 * k;        // permuted column slot
                hb4[rr][pos] = make_float4(m[k].x, m[k].y, s[k].x, s[k].y);
            }
        } else {
            const float4 z = make_float4(0.f, 0.f, 0.f, 0.f);
#pragma unroll
            for (int k = 0; k < 8; ++k) hb4[rr][g + 4 * k] = z;
        }
    }
    __syncthreads();

    // ========== vertical pass + SSIM epilogue: 4 rows/thread ==========
    const int tx  = tid & 31;
    const int ty  = tid >> 5;
    const int r0  = ty * 4;
    const int pos = (tx >> 3) + ((tx & 7) << 2); // same permutation as writer

    v2f vm[4], vs[4];
#pragma unroll
    for (int k = 0; k < 4; ++k) { vm[k] = (v2f)(0.f); vs[k] = (v2f)(0.f); }

#pragma unroll
    for (int t = 0; t < 14; ++t) {       // staged rows r0 .. r0+13
        const float4 h = hb4[r0 + t][pos];
        const v2f a = { h.x, h.y };      // (mu_u, mu_v)
        const v2f d = { h.z, h.w };      // (Su, Sv)
#pragma unroll
        for (int k = 0; k < 4; ++k) {
            const int u = t - k;
            if (u >= 0 && u < KW) {
                vm[k] += (W[u] * RT_HALF) * a;   // pk_fma, const folded
                vs[k] += (W[u] * 0.5f)    * d;   // pk_fma, const folded
            }
        }
    }

    float lsum = 0.f;
#pragma unroll
    for (int k = 0; k < 4; ++k) {
        const v2f sq = vm[k] * vm[k];    // (A, B) = 0.5*(mu_u^2, mu_v^2)
        const float A = sq.x, B = sq.y;
        const float Hu = vs[k].x, Hv = vs[k].y;   // 0.5*(Su, Sv)
        const float AmB = A - B, ApB = A + B;
        const float t1 = AmB + C1f;               // 2 mux muy + C1
        const float t2 = (Hu - Hv) - AmB + C2f;   // 2 sxy + C2
        const float t3 = ApB + C1f;               // mux^2+muy^2 + C1
        const float t4 = (Hu + Hv) - ApB + C2f;   // sx+sy + C2  (>= C2 > 0)
        float ssim = (t1 * t2) * __builtin_amdgcn_rcpf(t3 * t4);
        ssim = fminf(fmaxf(ssim, -1.f + 1e-6f), 1.f - 1e-6f);
        lsum += ssim;
    }

    // ========== block reduction + fence-free packed-atomic finalize ==========
#pragma unroll
    for (int off = 32; off > 0; off >>= 1)
        lsum += __shfl_down(lsum, off, 64);
    if ((tid & 63) == 0) red[tid >> 6] = lsum;
    __syncthreads();
    if (tid == 0) {
        const float s = red[0] + red[1] + red[2] + red[3];
        const int fid  = ((b * GY) + tr) * GX + tc;
        const int slot = fid & (NSLOTS - 1);

        const long long v = (long long)llrintf(s * SCALEF);   // |v| <= 2^34
        const unsigned long long sAdd =
            (1ull << SSHIFT) | (unsigned long long)(v + BIAS1);
        unsigned long long old = atomicAdd(&ws[16 * slot], sAdd);
        if ((old >> SSHIFT) == (unsigned long long)(PERSLOT - 1)) {
            const long long slotSum =
                (long long)((old & ((1ull << SSHIFT) - 1)) +
                            (unsigned long long)(v + BIAS1))
                - (long long)PERSLOT * BIAS1;
            const unsigned long long gAdd =
                (1ull << GSHIFT) | (unsigned long long)(slotSum + BIAS2);
            unsigned long long gold = atomicAdd(&ws[16 * NSLOTS], gAdd);
            if ((gold >> GSHIFT) == (unsigned long long)(NSLOTS - 1)) {
                const long long total =
                    (long long)((gold & ((1ull << GSHIFT) - 1)) +
                                (unsigned long long)(slotSum + BIAS2))
                    - (long long)NSLOTS * BIAS2;
                const double mean =
                    (double)total / ((double)SCALEF * (double)NBLOCKS * (double)(TW * TH));
                out[0] = (float)(1.0 - mean);
            }
        }
    }
}

extern "C" void kernel_launch(void* const* d_in, const int* in_sizes, int n_in,
                              void* d_out, int out_size, void* d_ws, size_t ws_size,
                              hipStream_t stream) {
    const float* x = (const float*)d_in[0];
    const float* y = (const float*)d_in[1];
    float* out = (float*)d_out;
    unsigned long long* ws = (unsigned long long*)d_ws;

    hipMemsetAsync(d_ws, 0, (NSLOTS + 1) * 128, stream);
    dim3 grid(GX, GY, NBATCH);
    ssim_fused_kernel<<<grid, 256, 0, stream>>>(x, y, out, ws);
}